// Round 1
// baseline (1708.509 us; speedup 1.0000x reference)
//
#include <hip/hip_runtime.h>
#include <cmath>

#define MSG 128
#define TILE_M 128
#define LDSTRIDE 136  // bf16 elements per LDS row (128 + 8 pad)

typedef __attribute__((ext_vector_type(8))) __bf16 bf16x8;
typedef __attribute__((ext_vector_type(4))) float f32x4;

__device__ __forceinline__ unsigned short f2bf(float f) {
  union { float f; unsigned u; } v; v.f = f;
  unsigned r = v.u + 0x7FFFu + ((v.u >> 16) & 1u);  // round-to-nearest-even
  return (unsigned short)(r >> 16);
}

// ---- Kernel 1: convert + transpose both hidden-layer weight matrices to bf16.
// Wt[n][k] = W1[k][n]  so MFMA B-fragments (contiguous in k) are vector loads.
__global__ void prep_weights_kernel(const float* __restrict__ Ww1,
                                    const float* __restrict__ Wa1,
                                    unsigned short* __restrict__ WtW,
                                    unsigned short* __restrict__ WtA) {
  int idx = blockIdx.x * blockDim.x + threadIdx.x;
  if (idx < MSG * MSG) {
    int k = idx >> 7;
    int n = idx & 127;
    WtW[n * MSG + k] = f2bf(Ww1[idx]);
    WtA[n * MSG + k] = f2bf(Wa1[idx]);
  }
}

// ---- Kernel 2: fused edge MLPs (weights + attention) via bf16 MFMA.
// Block = 256 threads = 4 waves, handles TILE_M=128 edges.
// Wave w computes rows [32w, 32w+32) x all 128 hidden units, then fuses the
// second linear (SiLU -> dot W2 -> +b2) in the epilogue.
__global__ __launch_bounds__(256, 2)
void edge_mlp_kernel(const float* __restrict__ m_ij,
                     const unsigned short* __restrict__ WtW,
                     const unsigned short* __restrict__ WtA,
                     const float* __restrict__ bw1, const float* __restrict__ Ww2,
                     const float* __restrict__ bw2,
                     const float* __restrict__ ba1, const float* __restrict__ Wa2,
                     const float* __restrict__ ba2,
                     const int* __restrict__ src,
                     float* __restrict__ w_raw, float* __restrict__ a_ij,
                     float* __restrict__ a_i, int E) {
  __shared__ __align__(16) unsigned short mlds[TILE_M * LDSTRIDE];
  const int tid = threadIdx.x;
  const int e0 = blockIdx.x * TILE_M;

  // Stage 128x128 fp32 tile of m_ij -> bf16 LDS. 4096 float4 chunks / 256 thr.
  #pragma unroll
  for (int i = 0; i < 16; ++i) {
    int c = i * 256 + tid;
    int row = c >> 5;          // 32 float4 per row
    int col4 = c & 31;
    int e = e0 + row;
    if (e >= E) e = E - 1;     // clamp (E % 128 == 0 in practice)
    const float4 v = *(const float4*)(m_ij + ((size_t)e * MSG + col4 * 4));
    uint2 p;
    p.x = (unsigned)f2bf(v.x) | ((unsigned)f2bf(v.y) << 16);
    p.y = (unsigned)f2bf(v.z) | ((unsigned)f2bf(v.w) << 16);
    *(uint2*)(&mlds[row * LDSTRIDE + col4 * 4]) = p;
  }
  __syncthreads();

  const int w = tid >> 6;
  const int lane = tid & 63;
  const int quad = lane >> 4;   // lane>>4
  const int l16 = lane & 15;
  const int r0 = w * 32;

  // A-fragment LDS base: A[m = lane&15][k = quad*8 + j]  (verified layout)
  const unsigned short* a0p = &mlds[(r0 + l16) * LDSTRIDE + quad * 8];
  const unsigned short* a1p = a0p + 16 * LDSTRIDE;

  auto run_mlp = [&](const unsigned short* __restrict__ Wt,
                     const float* __restrict__ b1, const float* __restrict__ W2,
                     float b2, bool isAtt) {
    f32x4 acc0[8], acc1[8];
    #pragma unroll
    for (int nt = 0; nt < 8; ++nt) {
      acc0[nt] = {0.f, 0.f, 0.f, 0.f};
      acc1[nt] = {0.f, 0.f, 0.f, 0.f};
    }
    // B-fragment: B[k = quad*8+j][n = lane&15], from transposed weights
    const unsigned short* bbase = Wt + (size_t)l16 * MSG + quad * 8;
    #pragma unroll
    for (int kt = 0; kt < 4; ++kt) {
      bf16x8 A0 = *(const bf16x8*)(a0p + kt * 32);
      bf16x8 A1 = *(const bf16x8*)(a1p + kt * 32);
      #pragma unroll
      for (int nt = 0; nt < 8; ++nt) {
        bf16x8 B = *(const bf16x8*)(bbase + (size_t)nt * 16 * MSG + kt * 32);
        acc0[nt] = __builtin_amdgcn_mfma_f32_16x16x32_bf16(A0, B, acc0[nt], 0, 0, 0);
        acc1[nt] = __builtin_amdgcn_mfma_f32_16x16x32_bf16(A1, B, acc1[nt], 0, 0, 0);
      }
    }
    // Epilogue: fused second linear. Lane holds cols n = nt*16 + l16.
    float b1v[8], w2v[8];
    #pragma unroll
    for (int nt = 0; nt < 8; ++nt) {
      b1v[nt] = b1[nt * 16 + l16];
      w2v[nt] = W2[nt * 16 + l16];
    }
    float part[8];
    #pragma unroll
    for (int r = 0; r < 4; ++r) {
      float s0 = 0.f, s1 = 0.f;
      #pragma unroll
      for (int nt = 0; nt < 8; ++nt) {
        float h0 = acc0[nt][r] + b1v[nt];
        float h1 = acc1[nt][r] + b1v[nt];
        s0 += (h0 / (1.f + __expf(-h0))) * w2v[nt];  // silu(h)*W2
        s1 += (h1 / (1.f + __expf(-h1))) * w2v[nt];
      }
      part[r] = s0;
      part[4 + r] = s1;
    }
    // Reduce across the 16 lanes of each quad (rows live per-quad in C layout)
    #pragma unroll
    for (int i = 0; i < 8; ++i) {
      #pragma unroll
      for (int off = 1; off < 16; off <<= 1)
        part[i] += __shfl_xor(part[i], off, 64);
    }
    // C/D layout: row-within-tile = quad*4 + reg. part[i]: mt=i>>2, r=i&3.
    #pragma unroll
    for (int i = 0; i < 8; ++i) {
      if (l16 == i) {
        int row = r0 + (i >> 2) * 16 + quad * 4 + (i & 3);
        int e = e0 + row;
        if (e < E) {
          float val = part[i] + b2;
          if (isAtt) {
            float a = __expf(val);
            a_ij[e] = a;
            atomicAdd(&a_i[src[e]], a);
          } else {
            w_raw[e] = val;
          }
        }
      }
    }
  };

  run_mlp(WtW, bw1, Ww2, bw2[0], false);
  run_mlp(WtA, ba1, Wa2, ba2[0], true);
}

// ---- Kernel 3: per-edge scatter of weighted unit position differences.
__global__ void scatter_kernel(const float* __restrict__ x,
                               const int* __restrict__ src,
                               const int* __restrict__ dst,
                               const float* __restrict__ w_raw,
                               const float* __restrict__ a_ij,
                               const float* __restrict__ a_i,
                               float* __restrict__ out, int E) {
  int e = blockIdx.x * blockDim.x + threadIdx.x;
  if (e >= E) return;
  int s = src[e];
  int d = dst[e];
  float w = w_raw[e] * (a_ij[e] / a_i[s]);
  float sx = x[3 * s], sy = x[3 * s + 1], sz = x[3 * s + 2];
  float dx = x[3 * d] - sx;
  float dy = x[3 * d + 1] - sy;
  float dz = x[3 * d + 2] - sz;
  float nrm = sqrtf(dx * dx + dy * dy + dz * dz);
  nrm = fmaxf(nrm, 1e-12f);
  float inv = w / nrm;
  atomicAdd(&out[3 * s + 0], dx * inv);
  atomicAdd(&out[3 * s + 1], dy * inv);
  atomicAdd(&out[3 * s + 2], dz * inv);
}

extern "C" void kernel_launch(void* const* d_in, const int* in_sizes, int n_in,
                              void* d_out, int out_size, void* d_ws, size_t ws_size,
                              hipStream_t stream) {
  const float* x    = (const float*)d_in[0];
  const float* m_ij = (const float*)d_in[1];
  const int*   edges = (const int*)d_in[2];
  const float* Ww1 = (const float*)d_in[3];
  const float* bw1 = (const float*)d_in[4];
  const float* Ww2 = (const float*)d_in[5];
  const float* bw2 = (const float*)d_in[6];
  const float* Wa1 = (const float*)d_in[7];
  const float* ba1 = (const float*)d_in[8];
  const float* Wa2 = (const float*)d_in[9];
  const float* ba2 = (const float*)d_in[10];

  const int N = in_sizes[0] / 3;
  const int E = in_sizes[1] / MSG;
  const int* src = edges;        // edges[0] = receiver
  const int* dst = edges + E;    // edges[1] = neighbor

  // Workspace layout (~13.3 MB)
  char* p = (char*)d_ws;
  unsigned short* WtW = (unsigned short*)p; p += (size_t)MSG * MSG * 2;
  unsigned short* WtA = (unsigned short*)p; p += (size_t)MSG * MSG * 2;
  float* w_raw = (float*)p; p += (size_t)E * 4;
  float* aij   = (float*)p; p += (size_t)E * 4;
  float* ai    = (float*)p; p += (size_t)N * 4;

  float* out = (float*)d_out;

  hipMemsetAsync(ai, 0, (size_t)N * 4, stream);
  prep_weights_kernel<<<(MSG * MSG + 255) / 256, 256, 0, stream>>>(Ww1, Wa1, WtW, WtA);
  edge_mlp_kernel<<<(E + TILE_M - 1) / TILE_M, 256, 0, stream>>>(
      m_ij, WtW, WtA, bw1, Ww2, bw2, ba1, Wa2, ba2, src, w_raw, aij, ai, E);
  hipMemcpyAsync(out, x, (size_t)N * 3 * sizeof(float), hipMemcpyDeviceToDevice, stream);
  scatter_kernel<<<(E + 255) / 256, 256, 0, stream>>>(x, src, dst, w_raw, aij, ai, out, E);
}